// Round 1
// baseline (226.116 us; speedup 1.0000x reference)
//
#include <hip/hip_runtime.h>
#include <math.h>

#define NDIM 1024
#define HDIM 128
#define NB 256
#define NT 72
#define NR 36

__device__ __forceinline__ float wave_sum(float v) {
#pragma unroll
  for (int off = 32; off > 0; off >>= 1) v += __shfl_down(v, off, 64);
  return v;
}

__device__ __forceinline__ float dot4(const float4 a, const float4 b) {
  return a.x * b.x + a.y * b.y + a.z * b.z + a.w * b.w;
}

// K1: img_repr = mean over 36 regions; img_n = l2norm(img_repr)
__global__ void k_img(const float* __restrict__ img, float* __restrict__ repr,
                      float* __restrict__ imgn) {
  const int b = blockIdx.x, tid = threadIdx.x;
  const float* base = img + (size_t)b * NR * NDIM + tid * 4;
  float sx = 0.f, sy = 0.f, sz = 0.f, sw = 0.f;
#pragma unroll 4
  for (int r = 0; r < NR; ++r) {
    const float4 v = *reinterpret_cast<const float4*>(base + r * NDIM);
    sx += v.x; sy += v.y; sz += v.z; sw += v.w;
  }
  const float inv = 1.0f / (float)NR;
  sx *= inv; sy *= inv; sz *= inv; sw *= inv;
  *reinterpret_cast<float4*>(repr + b * NDIM + tid * 4) = make_float4(sx, sy, sz, sw);
  float sq = wave_sum(sx * sx + sy * sy + sz * sz + sw * sw);
  __shared__ float red[4];
  __shared__ float invn;
  const int lane = tid & 63, wv = tid >> 6;
  if (lane == 0) red[wv] = sq;
  __syncthreads();
  if (tid == 0) invn = 1.0f / (sqrtf(red[0] + red[1] + red[2] + red[3]) + 1e-8f);
  __syncthreads();
  const float iv = invn;
  *reinterpret_cast<float4*>(imgn + b * NDIM + tid * 4) =
      make_float4(sx * iv, sy * iv, sz * iv, sw * iv);
}

// K2: one pass over cap_embed: per-(b,d) full sum, sum of squares, masked sum
__global__ void k_cap1(const float* __restrict__ cap, const int* __restrict__ lens,
                       float* __restrict__ fullsum, float* __restrict__ fullsq,
                       float* __restrict__ msum) {
  const int b = blockIdx.x, tid = threadIdx.x;
  const int len = lens[b];
  const float* base = cap + (size_t)b * NT * NDIM + tid * 4;
  float fsx = 0.f, fsy = 0.f, fsz = 0.f, fsw = 0.f;
  float fqx = 0.f, fqy = 0.f, fqz = 0.f, fqw = 0.f;
  float msx = 0.f, msy = 0.f, msz = 0.f, msw = 0.f;
  for (int t = 0; t < NT; ++t) {
    const float4 v = *reinterpret_cast<const float4*>(base + t * NDIM);
    fsx += v.x; fsy += v.y; fsz += v.z; fsw += v.w;
    fqx += v.x * v.x; fqy += v.y * v.y; fqz += v.z * v.z; fqw += v.w * v.w;
    if (t < len) { msx += v.x; msy += v.y; msz += v.z; msw += v.w; }
  }
  const int o = b * NDIM + tid * 4;
  *reinterpret_cast<float4*>(fullsum + o) = make_float4(fsx, fsy, fsz, fsw);
  *reinterpret_cast<float4*>(fullsq + o) = make_float4(fqx, fqy, fqz, fqw);
  *reinterpret_cast<float4*>(msum + o) = make_float4(msx, msy, msz, msw);
}

// K3: per-feature BN stats
__global__ void k_stats(const float* __restrict__ fullsum, const float* __restrict__ fullsq,
                        float* __restrict__ meanv, float* __restrict__ rstdv) {
  const int d = blockIdx.x * 256 + threadIdx.x;
  float s = 0.f, q = 0.f;
  for (int b = 0; b < NB; ++b) { s += fullsum[b * NDIM + d]; q += fullsq[b * NDIM + d]; }
  const float invN = 1.0f / (float)(NB * NT);
  const float m = s * invN;
  const float var = q * invN - m * m;
  meanv[d] = m;
  rstdv[d] = 1.0f / sqrtf(var + 1e-5f);
}

// K4: pooled and pooled^2
__global__ void k_pool(const float* __restrict__ msum, const int* __restrict__ lens,
                       const float* __restrict__ meanv, const float* __restrict__ rstdv,
                       float* __restrict__ pooled, float* __restrict__ p2) {
  const int b = blockIdx.x, tid = threadIdx.x;
  const float invl = 1.0f / (float)lens[b];
  const int d = tid * 4;
  const float4 m = *reinterpret_cast<const float4*>(msum + b * NDIM + d);
  const float4 mu = *reinterpret_cast<const float4*>(meanv + d);
  const float4 rs = *reinterpret_cast<const float4*>(rstdv + d);
  const float px = (m.x * invl - mu.x) * rs.x;
  const float py = (m.y * invl - mu.y) * rs.y;
  const float pz = (m.z * invl - mu.z) * rs.z;
  const float pw = (m.w * invl - mu.w) * rs.w;
  *reinterpret_cast<float4*>(pooled + b * NDIM + d) = make_float4(px, py, pz, pw);
  *reinterpret_cast<float4*>(p2 + b * NDIM + d) = make_float4(px * px, py * py, pz * pz, pw * pw);
}

// K5: hidden = relu(img_repr @ W1 + b1), both branches; 8 images per block
__global__ void k_hidden(const float* __restrict__ repr, const float* __restrict__ Wg1,
                         const float* __restrict__ bg1, const float* __restrict__ Wb1,
                         const float* __restrict__ bb1, float* __restrict__ hg,
                         float* __restrict__ hb) {
  const int h = threadIdx.x;  // 0..127
  const int b0 = blockIdx.x * 8;
  __shared__ float sh[8 * NDIM];
  float4* shv = reinterpret_cast<float4*>(sh);
  const float4* src = reinterpret_cast<const float4*>(repr + (size_t)b0 * NDIM);
  for (int i = h; i < 8 * NDIM / 4; i += 128) shv[i] = src[i];
  __syncthreads();
  float ag[8] = {0, 0, 0, 0, 0, 0, 0, 0}, ab[8] = {0, 0, 0, 0, 0, 0, 0, 0};
  for (int d = 0; d < NDIM; ++d) {
    const float wg = Wg1[d * HDIM + h];
    const float wb = Wb1[d * HDIM + h];
#pragma unroll
    for (int k = 0; k < 8; ++k) {
      const float x = sh[k * NDIM + d];
      ag[k] += x * wg;
      ab[k] += x * wb;
    }
  }
  const float bgv = bg1[h], bbv = bb1[h];
#pragma unroll
  for (int k = 0; k < 8; ++k) {
    hg[(b0 + k) * HDIM + h] = fmaxf(ag[k] + bgv, 0.0f);
    hb[(b0 + k) * HDIM + h] = fmaxf(ab[k] + bbv, 0.0f);
  }
}

// K6: gamma/beta output layer + derived u,a,bv,c,e; 4 images per block
__global__ void k_gamma(const float* __restrict__ hg, const float* __restrict__ hb,
                        const float* __restrict__ Wg2, const float* __restrict__ bg2,
                        const float* __restrict__ Wb2, const float* __restrict__ bb2,
                        const float* __restrict__ imgn, float* __restrict__ uarr,
                        float* __restrict__ aarr, float* __restrict__ bvarr,
                        float* __restrict__ cvec, float* __restrict__ evec) {
  const int tid = threadIdx.x;
  const int b0 = blockIdx.x * 4;
  __shared__ float shg[4][HDIM], shb[4][HDIM];
  for (int i = tid; i < 4 * HDIM; i += 256) {
    shg[i >> 7][i & 127] = hg[b0 * HDIM + i];
    shb[i >> 7][i & 127] = hb[b0 * HDIM + i];
  }
  __syncthreads();
  const int d = tid * 4;
  float gx[4] = {0, 0, 0, 0}, gy[4] = {0, 0, 0, 0}, gz[4] = {0, 0, 0, 0}, gw[4] = {0, 0, 0, 0};
  float bxx[4] = {0, 0, 0, 0}, byy[4] = {0, 0, 0, 0}, bzz[4] = {0, 0, 0, 0}, bww[4] = {0, 0, 0, 0};
  for (int h = 0; h < HDIM; ++h) {
    const float4 wg = *reinterpret_cast<const float4*>(Wg2 + h * NDIM + d);
    const float4 wb = *reinterpret_cast<const float4*>(Wb2 + h * NDIM + d);
#pragma unroll
    for (int k = 0; k < 4; ++k) {
      const float hgv = shg[k][h], hbv = shb[k][h];
      gx[k] += hgv * wg.x; gy[k] += hgv * wg.y; gz[k] += hgv * wg.z; gw[k] += hgv * wg.w;
      bxx[k] += hbv * wb.x; byy[k] += hbv * wb.y; bzz[k] += hbv * wb.z; bww[k] += hbv * wb.w;
    }
  }
  const float4 bgv = *reinterpret_cast<const float4*>(bg2 + d);
  const float4 bbv = *reinterpret_cast<const float4*>(bb2 + d);
  __shared__ float sc[4][4], se[4][4];
  const int lane = tid & 63, wv = tid >> 6;
#pragma unroll
  for (int k = 0; k < 4; ++k) {
    const float ox = gx[k] + bgv.x + 1.0f, oy = gy[k] + bgv.y + 1.0f;
    const float oz = gz[k] + bgv.z + 1.0f, ow = gw[k] + bgv.w + 1.0f;
    const float tbx = bxx[k] + bbv.x, tby = byy[k] + bbv.y;
    const float tbz = bzz[k] + bbv.z, tbw = bww[k] + bbv.w;
    const float4 nv = *reinterpret_cast<const float4*>(imgn + (size_t)(b0 + k) * NDIM + d);
    *reinterpret_cast<float4*>(uarr + (size_t)(b0 + k) * NDIM + d) =
        make_float4(nv.x * ox, nv.y * oy, nv.z * oz, nv.w * ow);
    *reinterpret_cast<float4*>(aarr + (size_t)(b0 + k) * NDIM + d) =
        make_float4(ox * ox, oy * oy, oz * oz, ow * ow);
    *reinterpret_cast<float4*>(bvarr + (size_t)(b0 + k) * NDIM + d) =
        make_float4(ox * tbx, oy * tby, oz * tbz, ow * tbw);
    const float cp = wave_sum(nv.x * tbx + nv.y * tby + nv.z * tbz + nv.w * tbw);
    const float ep = wave_sum(tbx * tbx + tby * tby + tbz * tbz + tbw * tbw);
    if (lane == 0) { sc[k][wv] = cp; se[k][wv] = ep; }
  }
  __syncthreads();
  if (tid < 4) {
    cvec[b0 + tid] = sc[tid][0] + sc[tid][1] + sc[tid][2] + sc[tid][3];
    evec[b0 + tid] = se[tid][0] + se[tid][1] + se[tid][2] + se[tid][3];
  }
}

// K7: fused 3-dot tile kernel; 32x32 output tile, 2x2 per thread, split-K=4
#define DC 32
__global__ void k_simtile(const float* __restrict__ uarr, const float* __restrict__ aarr,
                          const float* __restrict__ bvarr, const float* __restrict__ pooled,
                          const float* __restrict__ p2, float* __restrict__ pn,
                          float* __restrict__ pa, float* __restrict__ pb) {
  __shared__ float su[32][36], sa[32][36], sb[32][36], sp[32][36], sq[32][36];
  const int tid = threadIdx.x;
  const int tx = tid & 15, ty = tid >> 4;
  const int i0 = blockIdx.x * 32, j0 = blockIdx.y * 32;
  const int k0 = blockIdx.z * 256;
  const int lr = tid >> 3;        // 0..31
  const int lc = (tid & 7) * 4;   // 0..28
  float an00 = 0, an01 = 0, an10 = 0, an11 = 0;
  float aa00 = 0, aa01 = 0, aa10 = 0, aa11 = 0;
  float ab00 = 0, ab01 = 0, ab10 = 0, ab11 = 0;
  for (int dc = k0; dc < k0 + 256; dc += DC) {
    __syncthreads();
    *reinterpret_cast<float4*>(&su[lr][lc]) =
        *reinterpret_cast<const float4*>(uarr + (i0 + lr) * NDIM + dc + lc);
    *reinterpret_cast<float4*>(&sa[lr][lc]) =
        *reinterpret_cast<const float4*>(aarr + (i0 + lr) * NDIM + dc + lc);
    *reinterpret_cast<float4*>(&sb[lr][lc]) =
        *reinterpret_cast<const float4*>(bvarr + (i0 + lr) * NDIM + dc + lc);
    *reinterpret_cast<float4*>(&sp[lr][lc]) =
        *reinterpret_cast<const float4*>(pooled + (j0 + lr) * NDIM + dc + lc);
    *reinterpret_cast<float4*>(&sq[lr][lc]) =
        *reinterpret_cast<const float4*>(p2 + (j0 + lr) * NDIM + dc + lc);
    __syncthreads();
#pragma unroll
    for (int dd = 0; dd < DC; dd += 4) {
      const float4 ru0 = *reinterpret_cast<const float4*>(&su[tx][dd]);
      const float4 ru1 = *reinterpret_cast<const float4*>(&su[tx + 16][dd]);
      const float4 ra0 = *reinterpret_cast<const float4*>(&sa[tx][dd]);
      const float4 ra1 = *reinterpret_cast<const float4*>(&sa[tx + 16][dd]);
      const float4 rb0 = *reinterpret_cast<const float4*>(&sb[tx][dd]);
      const float4 rb1 = *reinterpret_cast<const float4*>(&sb[tx + 16][dd]);
      const float4 rp0 = *reinterpret_cast<const float4*>(&sp[ty][dd]);
      const float4 rp1 = *reinterpret_cast<const float4*>(&sp[ty + 16][dd]);
      const float4 rq0 = *reinterpret_cast<const float4*>(&sq[ty][dd]);
      const float4 rq1 = *reinterpret_cast<const float4*>(&sq[ty + 16][dd]);
      an00 += dot4(ru0, rp0); an01 += dot4(ru0, rp1);
      an10 += dot4(ru1, rp0); an11 += dot4(ru1, rp1);
      aa00 += dot4(ra0, rq0); aa01 += dot4(ra0, rq1);
      aa10 += dot4(ra1, rq0); aa11 += dot4(ra1, rq1);
      ab00 += dot4(rb0, rp0); ab01 += dot4(rb0, rp1);
      ab10 += dot4(rb1, rp0); ab11 += dot4(rb1, rp1);
    }
  }
  const int s = blockIdx.z;
  {
    const int i = i0 + tx, j = j0 + ty;
    size_t o = ((size_t)s * 256 + j) * 256 + i;
    pn[o] = an00; pa[o] = aa00; pb[o] = ab00;
    o = ((size_t)s * 256 + (j + 16)) * 256 + i;
    pn[o] = an01; pa[o] = aa01; pb[o] = ab01;
    o = ((size_t)s * 256 + j) * 256 + (i + 16);
    pn[o] = an10; pa[o] = aa10; pb[o] = ab10;
    o = ((size_t)s * 256 + (j + 16)) * 256 + (i + 16);
    pn[o] = an11; pa[o] = aa11; pb[o] = ab11;
  }
}

// K8: split-K combine + epilogue
__global__ void k_reduce(const float* __restrict__ pn, const float* __restrict__ pa,
                         const float* __restrict__ pb, const float* __restrict__ cvec,
                         const float* __restrict__ evec, float* __restrict__ out) {
  const int j = blockIdx.x, i = threadIdx.x;
  const size_t base = (size_t)j * 256 + i;
  float n = 0.f, a = 0.f, b2 = 0.f;
#pragma unroll
  for (int s = 0; s < 4; ++s) {
    const size_t o = base + (size_t)s * 65536;
    n += pn[o]; a += pa[o]; b2 += pb[o];
  }
  const float num = n + cvec[i];
  const float den2 = a + 2.0f * b2 + evec[i];
  out[base] = num / (sqrtf(fmaxf(den2, 0.0f)) + 1e-8f);
}

extern "C" void kernel_launch(void* const* d_in, const int* in_sizes, int n_in,
                              void* d_out, int out_size, void* d_ws, size_t ws_size,
                              hipStream_t stream) {
  const float* img = (const float*)d_in[0];
  const float* cap = (const float*)d_in[1];
  const int* lens = (const int*)d_in[2];
  const float* Wg1 = (const float*)d_in[3];
  const float* bg1 = (const float*)d_in[4];
  const float* Wg2 = (const float*)d_in[5];
  const float* bg2 = (const float*)d_in[6];
  const float* Wb1 = (const float*)d_in[7];
  const float* bb1 = (const float*)d_in[8];
  const float* Wb2 = (const float*)d_in[9];
  const float* bb2 = (const float*)d_in[10];
  float* out = (float*)d_out;

  float* w = (float*)d_ws;
  float* repr = w;    w += NB * NDIM;
  float* imgn = w;    w += NB * NDIM;
  float* fullsum = w; w += NB * NDIM;
  float* fullsq = w;  w += NB * NDIM;
  float* msum = w;    w += NB * NDIM;
  float* pooled = w;  w += NB * NDIM;
  float* p2 = w;      w += NB * NDIM;
  float* uarr = w;    w += NB * NDIM;
  float* aarr = w;    w += NB * NDIM;
  float* bvarr = w;   w += NB * NDIM;
  float* hg = w;      w += NB * HDIM;
  float* hb = w;      w += NB * HDIM;
  float* meanv = w;   w += NDIM;
  float* rstdv = w;   w += NDIM;
  float* cvec = w;    w += NB;
  float* evec = w;    w += NB;
  // split-K partials alias buffers that are dead by the time k_simtile runs
  float* pn = fullsum;  // dead after k_stats
  float* pa = fullsq;   // dead after k_stats
  float* pb = msum;     // dead after k_pool

  hipLaunchKernelGGL(k_img, dim3(NB), dim3(256), 0, stream, img, repr, imgn);
  hipLaunchKernelGGL(k_cap1, dim3(NB), dim3(256), 0, stream, cap, lens, fullsum, fullsq, msum);
  hipLaunchKernelGGL(k_stats, dim3(4), dim3(256), 0, stream, fullsum, fullsq, meanv, rstdv);
  hipLaunchKernelGGL(k_pool, dim3(NB), dim3(256), 0, stream, msum, lens, meanv, rstdv, pooled, p2);
  hipLaunchKernelGGL(k_hidden, dim3(32), dim3(128), 0, stream, repr, Wg1, bg1, Wb1, bb1, hg, hb);
  hipLaunchKernelGGL(k_gamma, dim3(64), dim3(256), 0, stream, hg, hb, Wg2, bg2, Wb2, bb2, imgn,
                     uarr, aarr, bvarr, cvec, evec);
  hipLaunchKernelGGL(k_simtile, dim3(8, 8, 4), dim3(256), 0, stream, uarr, aarr, bvarr, pooled,
                     p2, pn, pa, pb);
  hipLaunchKernelGGL(k_reduce, dim3(NB), dim3(256), 0, stream, pn, pa, pb, cvec, evec, out);
}

// Round 2
// 91.294 us; speedup vs baseline: 2.4768x; 2.4768x over previous
//
#include <hip/hip_runtime.h>
#include <math.h>

#define NDIM 1024
#define HDIM 128
#define NB 256
#define NT 72
#define NR 36

__device__ __forceinline__ float wave_sum(float v) {
#pragma unroll
  for (int off = 32; off > 0; off >>= 1) v += __shfl_down(v, off, 64);
  return v;
}

__device__ __forceinline__ float dot4(const float4 a, const float4 b) {
  return a.x * b.x + a.y * b.y + a.z * b.z + a.w * b.w;
}

// K1: per-(b,half) partial sums over cap_embed: full sum, sum sq, masked sum
__global__ __launch_bounds__(256) void k_cap1(const float* __restrict__ cap,
                                              const int* __restrict__ lens,
                                              float* __restrict__ fs, float* __restrict__ fq,
                                              float* __restrict__ ms) {
  const int b = blockIdx.x & 255;
  const int half = blockIdx.x >> 8;
  const int tid = threadIdx.x;
  const int len = lens[b];
  const int t0 = half * 36;
  const float* base = cap + (size_t)b * NT * NDIM + (size_t)t0 * NDIM + tid * 4;
  float fsx = 0.f, fsy = 0.f, fsz = 0.f, fsw = 0.f;
  float fqx = 0.f, fqy = 0.f, fqz = 0.f, fqw = 0.f;
  float msx = 0.f, msy = 0.f, msz = 0.f, msw = 0.f;
#pragma unroll 12
  for (int tt = 0; tt < 36; ++tt) {
    const float4 v = *reinterpret_cast<const float4*>(base + tt * NDIM);
    fsx += v.x; fsy += v.y; fsz += v.z; fsw += v.w;
    fqx += v.x * v.x; fqy += v.y * v.y; fqz += v.z * v.z; fqw += v.w * v.w;
    if (t0 + tt < len) { msx += v.x; msy += v.y; msz += v.z; msw += v.w; }
  }
  const int o = (half * NB + b) * NDIM + tid * 4;
  *reinterpret_cast<float4*>(fs + o) = make_float4(fsx, fsy, fsz, fsw);
  *reinterpret_cast<float4*>(fq + o) = make_float4(fqx, fqy, fqz, fqw);
  *reinterpret_cast<float4*>(ms + o) = make_float4(msx, msy, msz, msw);
}

// K2: per-feature BN stats; reduce 512 partial rows. grid 16 x 256 threads.
__global__ __launch_bounds__(256) void k_stats(const float* __restrict__ fs,
                                               const float* __restrict__ fq,
                                               float* __restrict__ meanv,
                                               float* __restrict__ rstdv) {
  const int dloc = threadIdx.x & 63;
  const int grp = threadIdx.x >> 6;  // 0..3
  const int d = blockIdx.x * 64 + dloc;
  float s = 0.f, q = 0.f;
  const int r0 = grp * 128;
#pragma unroll 8
  for (int r = r0; r < r0 + 128; ++r) {
    s += fs[r * NDIM + d];
    q += fq[r * NDIM + d];
  }
  __shared__ float ss[4][64], sq2[4][64];
  ss[grp][dloc] = s;
  sq2[grp][dloc] = q;
  __syncthreads();
  if (threadIdx.x < 64) {
    s = ss[0][dloc] + ss[1][dloc] + ss[2][dloc] + ss[3][dloc];
    q = sq2[0][dloc] + sq2[1][dloc] + sq2[2][dloc] + sq2[3][dloc];
    const float invN = 1.0f / (float)(NB * NT);
    const float m = s * invN;
    const float var = q * invN - m * m;
    meanv[d] = m;
    rstdv[d] = 1.0f / sqrtf(var + 1e-5f);
  }
}

// K3: pooled and pooled^2 (combines the two time-halves of msum)
__global__ __launch_bounds__(256) void k_pool(const float* __restrict__ ms,
                                              const int* __restrict__ lens,
                                              const float* __restrict__ meanv,
                                              const float* __restrict__ rstdv,
                                              float* __restrict__ pooled, float* __restrict__ p2) {
  const int b = blockIdx.x, tid = threadIdx.x;
  const float invl = 1.0f / (float)lens[b];
  const int d = tid * 4;
  const float4 m0 = *reinterpret_cast<const float4*>(ms + (size_t)b * NDIM + d);
  const float4 m1 = *reinterpret_cast<const float4*>(ms + (size_t)(NB + b) * NDIM + d);
  const float4 mu = *reinterpret_cast<const float4*>(meanv + d);
  const float4 rs = *reinterpret_cast<const float4*>(rstdv + d);
  const float px = ((m0.x + m1.x) * invl - mu.x) * rs.x;
  const float py = ((m0.y + m1.y) * invl - mu.y) * rs.y;
  const float pz = ((m0.z + m1.z) * invl - mu.z) * rs.z;
  const float pw = ((m0.w + m1.w) * invl - mu.w) * rs.w;
  *reinterpret_cast<float4*>(pooled + b * NDIM + d) = make_float4(px, py, pz, pw);
  *reinterpret_cast<float4*>(p2 + b * NDIM + d) = make_float4(px * px, py * py, pz * pz, pw * pw);
}

// K4: fully fused per-image path: region-mean + l2norm + 2-layer MLP (both
// branches) + derived u, a, bv, c, e.  One block per image, 256 threads.
__global__ __launch_bounds__(256) void k_fused(
    const float* __restrict__ img, const float* __restrict__ Wg1, const float* __restrict__ bg1,
    const float* __restrict__ Wb1, const float* __restrict__ bb1, const float* __restrict__ Wg2,
    const float* __restrict__ bg2, const float* __restrict__ Wb2, const float* __restrict__ bb2,
    float* __restrict__ uarr, float* __restrict__ aarr, float* __restrict__ bvarr,
    float* __restrict__ cvec, float* __restrict__ evec) {
  const int b = blockIdx.x, tid = threadIdx.x;
  const int lane = tid & 63, wv = tid >> 6;
  __shared__ float shr[NDIM];
  __shared__ float pg[2][HDIM], pbm[2][HDIM];
  __shared__ float shh[2][HDIM];
  __shared__ float red[8];
  __shared__ float sInv;

  // ---- phase 0: mean over 36 regions + l2 norm factor ----
  const float* base = img + (size_t)b * NR * NDIM + tid * 4;
  float sx = 0.f, sy = 0.f, sz = 0.f, sw = 0.f;
#pragma unroll 12
  for (int r = 0; r < NR; ++r) {
    const float4 v = *reinterpret_cast<const float4*>(base + r * NDIM);
    sx += v.x; sy += v.y; sz += v.z; sw += v.w;
  }
  const float inv = 1.0f / (float)NR;
  sx *= inv; sy *= inv; sz *= inv; sw *= inv;
  *reinterpret_cast<float4*>(shr + tid * 4) = make_float4(sx, sy, sz, sw);
  const float sq = wave_sum(sx * sx + sy * sy + sz * sz + sw * sw);
  if (lane == 0) red[wv] = sq;
  __syncthreads();
  if (tid == 0) sInv = 1.0f / (sqrtf(red[0] + red[1] + red[2] + red[3]) + 1e-8f);
  __syncthreads();
  const float invn = sInv;

  // ---- phase 1: layer1, d-split across thread halves ----
  const int part = tid >> 7;     // 0,1 -> d range
  const int h = tid & 127;
  const int d0 = part * 512;
  float ag = 0.f, ab = 0.f;
#pragma unroll 16
  for (int d = d0; d < d0 + 512; ++d) {
    const float x = shr[d];
    ag += x * Wg1[d * HDIM + h];
    ab += x * Wb1[d * HDIM + h];
  }
  pg[part][h] = ag;
  pbm[part][h] = ab;
  __syncthreads();
  if (tid < 128) {
    shh[0][tid] = fmaxf(pg[0][tid] + pg[1][tid] + bg1[tid], 0.0f);
  } else {
    const int hh = tid - 128;
    shh[1][hh] = fmaxf(pbm[0][hh] + pbm[1][hh] + bb1[hh], 0.0f);
  }
  __syncthreads();

  // ---- phase 2: layer2 + derived quantities ----
  const int d = tid * 4;
  float gx = 0.f, gy = 0.f, gz = 0.f, gw = 0.f;
  float bx = 0.f, by = 0.f, bz = 0.f, bw = 0.f;
#pragma unroll 8
  for (int hh = 0; hh < HDIM; ++hh) {
    const float4 w2g = *reinterpret_cast<const float4*>(Wg2 + hh * NDIM + d);
    const float4 w2b = *reinterpret_cast<const float4*>(Wb2 + hh * NDIM + d);
    const float hgv = shh[0][hh], hbv = shh[1][hh];
    gx += hgv * w2g.x; gy += hgv * w2g.y; gz += hgv * w2g.z; gw += hgv * w2g.w;
    bx += hbv * w2b.x; by += hbv * w2b.y; bz += hbv * w2b.z; bw += hbv * w2b.w;
  }
  const float4 bg2v = *reinterpret_cast<const float4*>(bg2 + d);
  const float4 bb2v = *reinterpret_cast<const float4*>(bb2 + d);
  const float ox = gx + bg2v.x + 1.0f, oy = gy + bg2v.y + 1.0f;
  const float oz = gz + bg2v.z + 1.0f, ow = gw + bg2v.w + 1.0f;
  const float tbx = bx + bb2v.x, tby = by + bb2v.y;
  const float tbz = bz + bb2v.z, tbw = bw + bb2v.w;
  const float nx = sx * invn, ny = sy * invn, nz = sz * invn, nw = sw * invn;
  *reinterpret_cast<float4*>(uarr + (size_t)b * NDIM + d) =
      make_float4(nx * ox, ny * oy, nz * oz, nw * ow);
  *reinterpret_cast<float4*>(aarr + (size_t)b * NDIM + d) =
      make_float4(ox * ox, oy * oy, oz * oz, ow * ow);
  *reinterpret_cast<float4*>(bvarr + (size_t)b * NDIM + d) =
      make_float4(ox * tbx, oy * tby, oz * tbz, ow * tbw);
  const float cp = wave_sum(nx * tbx + ny * tby + nz * tbz + nw * tbw);
  const float ep = wave_sum(tbx * tbx + tby * tby + tbz * tbz + tbw * tbw);
  __syncthreads();  // red[] reuse
  if (lane == 0) { red[wv] = cp; red[4 + wv] = ep; }
  __syncthreads();
  if (tid == 0) {
    cvec[b] = red[0] + red[1] + red[2] + red[3];
    evec[b] = red[4] + red[5] + red[6] + red[7];
  }
}

// K5: fused 3-dot tile kernel; 32x32 output tile, 2x2 per thread, split-K=4
#define DC 32
__global__ __launch_bounds__(256) void k_simtile(
    const float* __restrict__ uarr, const float* __restrict__ aarr,
    const float* __restrict__ bvarr, const float* __restrict__ pooled,
    const float* __restrict__ p2, float* __restrict__ pn, float* __restrict__ pa,
    float* __restrict__ pb) {
  __shared__ float su[32][36], sa[32][36], sb[32][36], sp[32][36], sq[32][36];
  const int tid = threadIdx.x;
  const int tx = tid & 15, ty = tid >> 4;
  const int i0 = blockIdx.x * 32, j0 = blockIdx.y * 32;
  const int k0 = blockIdx.z * 256;
  const int lr = tid >> 3;       // 0..31
  const int lc = (tid & 7) * 4;  // 0..28
  float an00 = 0, an01 = 0, an10 = 0, an11 = 0;
  float aa00 = 0, aa01 = 0, aa10 = 0, aa11 = 0;
  float ab00 = 0, ab01 = 0, ab10 = 0, ab11 = 0;
  for (int dc = k0; dc < k0 + 256; dc += DC) {
    __syncthreads();
    *reinterpret_cast<float4*>(&su[lr][lc]) =
        *reinterpret_cast<const float4*>(uarr + (i0 + lr) * NDIM + dc + lc);
    *reinterpret_cast<float4*>(&sa[lr][lc]) =
        *reinterpret_cast<const float4*>(aarr + (i0 + lr) * NDIM + dc + lc);
    *reinterpret_cast<float4*>(&sb[lr][lc]) =
        *reinterpret_cast<const float4*>(bvarr + (i0 + lr) * NDIM + dc + lc);
    *reinterpret_cast<float4*>(&sp[lr][lc]) =
        *reinterpret_cast<const float4*>(pooled + (j0 + lr) * NDIM + dc + lc);
    *reinterpret_cast<float4*>(&sq[lr][lc]) =
        *reinterpret_cast<const float4*>(p2 + (j0 + lr) * NDIM + dc + lc);
    __syncthreads();
#pragma unroll
    for (int dd = 0; dd < DC; dd += 4) {
      const float4 ru0 = *reinterpret_cast<const float4*>(&su[tx][dd]);
      const float4 ru1 = *reinterpret_cast<const float4*>(&su[tx + 16][dd]);
      const float4 ra0 = *reinterpret_cast<const float4*>(&sa[tx][dd]);
      const float4 ra1 = *reinterpret_cast<const float4*>(&sa[tx + 16][dd]);
      const float4 rb0 = *reinterpret_cast<const float4*>(&sb[tx][dd]);
      const float4 rb1 = *reinterpret_cast<const float4*>(&sb[tx + 16][dd]);
      const float4 rp0 = *reinterpret_cast<const float4*>(&sp[ty][dd]);
      const float4 rp1 = *reinterpret_cast<const float4*>(&sp[ty + 16][dd]);
      const float4 rq0 = *reinterpret_cast<const float4*>(&sq[ty][dd]);
      const float4 rq1 = *reinterpret_cast<const float4*>(&sq[ty + 16][dd]);
      an00 += dot4(ru0, rp0); an01 += dot4(ru0, rp1);
      an10 += dot4(ru1, rp0); an11 += dot4(ru1, rp1);
      aa00 += dot4(ra0, rq0); aa01 += dot4(ra0, rq1);
      aa10 += dot4(ra1, rq0); aa11 += dot4(ra1, rq1);
      ab00 += dot4(rb0, rp0); ab01 += dot4(rb0, rp1);
      ab10 += dot4(rb1, rp0); ab11 += dot4(rb1, rp1);
    }
  }
  const int s = blockIdx.z;
  const int i = i0 + tx, j = j0 + ty;
  size_t o = ((size_t)s * 256 + j) * 256 + i;
  pn[o] = an00; pa[o] = aa00; pb[o] = ab00;
  o = ((size_t)s * 256 + (j + 16)) * 256 + i;
  pn[o] = an01; pa[o] = aa01; pb[o] = ab01;
  o = ((size_t)s * 256 + j) * 256 + (i + 16);
  pn[o] = an10; pa[o] = aa10; pb[o] = ab10;
  o = ((size_t)s * 256 + (j + 16)) * 256 + (i + 16);
  pn[o] = an11; pa[o] = aa11; pb[o] = ab11;
}

// K6: split-K combine + epilogue
__global__ __launch_bounds__(256) void k_reduce(const float* __restrict__ pn,
                                                const float* __restrict__ pa,
                                                const float* __restrict__ pb,
                                                const float* __restrict__ cvec,
                                                const float* __restrict__ evec,
                                                float* __restrict__ out) {
  const int j = blockIdx.x, i = threadIdx.x;
  const size_t base = (size_t)j * 256 + i;
  float n = 0.f, a = 0.f, b2 = 0.f;
#pragma unroll
  for (int s = 0; s < 4; ++s) {
    const size_t o = base + (size_t)s * 65536;
    n += pn[o]; a += pa[o]; b2 += pb[o];
  }
  const float num = n + cvec[i];
  const float den2 = a + 2.0f * b2 + evec[i];
  out[base] = num / (sqrtf(fmaxf(den2, 0.0f)) + 1e-8f);
}

extern "C" void kernel_launch(void* const* d_in, const int* in_sizes, int n_in,
                              void* d_out, int out_size, void* d_ws, size_t ws_size,
                              hipStream_t stream) {
  const float* img = (const float*)d_in[0];
  const float* cap = (const float*)d_in[1];
  const int* lens = (const int*)d_in[2];
  const float* Wg1 = (const float*)d_in[3];
  const float* bg1 = (const float*)d_in[4];
  const float* Wg2 = (const float*)d_in[5];
  const float* bg2 = (const float*)d_in[6];
  const float* Wb1 = (const float*)d_in[7];
  const float* bb1 = (const float*)d_in[8];
  const float* Wb2 = (const float*)d_in[9];
  const float* bb2 = (const float*)d_in[10];
  float* out = (float*)d_out;

  float* w = (float*)d_ws;
  float* fullsum = w; w += 2 * NB * NDIM;  // 512 partial rows
  float* fullsq = w;  w += 2 * NB * NDIM;
  float* msum = w;    w += 2 * NB * NDIM;
  float* pooled = w;  w += NB * NDIM;
  float* p2 = w;      w += NB * NDIM;
  float* uarr = w;    w += NB * NDIM;
  float* aarr = w;    w += NB * NDIM;
  float* bvarr = w;   w += NB * NDIM;
  float* meanv = w;   w += NDIM;
  float* rstdv = w;   w += NDIM;
  float* cvec = w;    w += NB;
  float* evec = w;    w += NB;
  // split-K partials (4*256*256 floats each) alias buffers dead after k_pool
  float* pn = fullsum;            // 262144 floats
  float* pa = fullsum + 262144;   // fullsum holds 524288 floats total
  float* pb = fullsq;

  hipLaunchKernelGGL(k_cap1, dim3(512), dim3(256), 0, stream, cap, lens, fullsum, fullsq, msum);
  hipLaunchKernelGGL(k_stats, dim3(16), dim3(256), 0, stream, fullsum, fullsq, meanv, rstdv);
  hipLaunchKernelGGL(k_pool, dim3(NB), dim3(256), 0, stream, msum, lens, meanv, rstdv, pooled, p2);
  hipLaunchKernelGGL(k_fused, dim3(NB), dim3(256), 0, stream, img, Wg1, bg1, Wb1, bb1, Wg2, bg2,
                     Wb2, bb2, uarr, aarr, bvarr, cvec, evec);
  hipLaunchKernelGGL(k_simtile, dim3(8, 8, 4), dim3(256), 0, stream, uarr, aarr, bvarr, pooled,
                     p2, pn, pa, pb);
  hipLaunchKernelGGL(k_reduce, dim3(NB), dim3(256), 0, stream, pn, pa, pb, cvec, evec, out);
}

// Round 3
// 84.272 us; speedup vs baseline: 2.6832x; 1.0833x over previous
//
#include <hip/hip_runtime.h>
#include <math.h>

#define NDIM 1024
#define HDIM 128
#define NB 256
#define NT 72
#define NR 36

__device__ __forceinline__ float wave_sum(float v) {
#pragma unroll
  for (int off = 32; off > 0; off >>= 1) v += __shfl_down(v, off, 64);
  return v;
}

__device__ __forceinline__ float dot4(const float4 a, const float4 b) {
  return a.x * b.x + a.y * b.y + a.z * b.z + a.w * b.w;
}

// K1: per-(b,half) partial sums over cap_embed: full sum, sum sq, masked sum
__global__ __launch_bounds__(256) void k_cap1(const float* __restrict__ cap,
                                              const int* __restrict__ lens,
                                              float* __restrict__ fs, float* __restrict__ fq,
                                              float* __restrict__ ms) {
  const int b = blockIdx.x & 255;
  const int half = blockIdx.x >> 8;
  const int tid = threadIdx.x;
  const int len = lens[b];
  const int t0 = half * 36;
  const float* base = cap + (size_t)b * NT * NDIM + (size_t)t0 * NDIM + tid * 4;
  float fsx = 0.f, fsy = 0.f, fsz = 0.f, fsw = 0.f;
  float fqx = 0.f, fqy = 0.f, fqz = 0.f, fqw = 0.f;
  float msx = 0.f, msy = 0.f, msz = 0.f, msw = 0.f;
#pragma unroll 12
  for (int tt = 0; tt < 36; ++tt) {
    const float4 v = *reinterpret_cast<const float4*>(base + tt * NDIM);
    fsx += v.x; fsy += v.y; fsz += v.z; fsw += v.w;
    fqx += v.x * v.x; fqy += v.y * v.y; fqz += v.z * v.z; fqw += v.w * v.w;
    if (t0 + tt < len) { msx += v.x; msy += v.y; msz += v.z; msw += v.w; }
  }
  const int o = (half * NB + b) * NDIM + tid * 4;
  *reinterpret_cast<float4*>(fs + o) = make_float4(fsx, fsy, fsz, fsw);
  *reinterpret_cast<float4*>(fq + o) = make_float4(fqx, fqy, fqz, fqw);
  *reinterpret_cast<float4*>(ms + o) = make_float4(msx, msy, msz, msw);
}

// K2: per-feature BN stats; reduce 512 partial rows
__global__ __launch_bounds__(256) void k_stats(const float* __restrict__ fs,
                                               const float* __restrict__ fq,
                                               float* __restrict__ meanv,
                                               float* __restrict__ rstdv) {
  const int dloc = threadIdx.x & 63;
  const int grp = threadIdx.x >> 6;
  const int d = blockIdx.x * 64 + dloc;
  float s = 0.f, q = 0.f;
  const int r0 = grp * 128;
#pragma unroll 8
  for (int r = r0; r < r0 + 128; ++r) {
    s += fs[r * NDIM + d];
    q += fq[r * NDIM + d];
  }
  __shared__ float ss[4][64], sq2[4][64];
  ss[grp][dloc] = s;
  sq2[grp][dloc] = q;
  __syncthreads();
  if (threadIdx.x < 64) {
    s = ss[0][dloc] + ss[1][dloc] + ss[2][dloc] + ss[3][dloc];
    q = sq2[0][dloc] + sq2[1][dloc] + sq2[2][dloc] + sq2[3][dloc];
    const float invN = 1.0f / (float)(NB * NT);
    const float m = s * invN;
    const float var = q * invN - m * m;
    meanv[d] = m;
    rstdv[d] = 1.0f / sqrtf(var + 1e-5f);
  }
}

// K3: pooled and pooled^2
__global__ __launch_bounds__(256) void k_pool(const float* __restrict__ ms,
                                              const int* __restrict__ lens,
                                              const float* __restrict__ meanv,
                                              const float* __restrict__ rstdv,
                                              float* __restrict__ pooled, float* __restrict__ p2) {
  const int b = blockIdx.x, tid = threadIdx.x;
  const float invl = 1.0f / (float)lens[b];
  const int d = tid * 4;
  const float4 m0 = *reinterpret_cast<const float4*>(ms + (size_t)b * NDIM + d);
  const float4 m1 = *reinterpret_cast<const float4*>(ms + (size_t)(NB + b) * NDIM + d);
  const float4 mu = *reinterpret_cast<const float4*>(meanv + d);
  const float4 rs = *reinterpret_cast<const float4*>(rstdv + d);
  const float px = ((m0.x + m1.x) * invl - mu.x) * rs.x;
  const float py = ((m0.y + m1.y) * invl - mu.y) * rs.y;
  const float pz = ((m0.z + m1.z) * invl - mu.z) * rs.z;
  const float pw = ((m0.w + m1.w) * invl - mu.w) * rs.w;
  *reinterpret_cast<float4*>(pooled + b * NDIM + d) = make_float4(px, py, pz, pw);
  *reinterpret_cast<float4*>(p2 + b * NDIM + d) = make_float4(px * px, py * py, pz * pz, pw * pw);
}

// K4: image mean over 36 regions + l2norm; 1024 threads, 16 waves/CU
__global__ __launch_bounds__(1024) void k_imgmean(const float* __restrict__ img,
                                                  float* __restrict__ repr,
                                                  float* __restrict__ imgn) {
  const int b = blockIdx.x, tid = threadIdx.x;
  const int col = tid & 255;  // float4 column
  const int rg = tid >> 8;    // region group 0..3 (9 regions each)
  __shared__ float4 part[4][256];
  __shared__ float red[4];
  __shared__ float sInv;
  const float* base = img + (size_t)b * NR * NDIM + (size_t)rg * 9 * NDIM + col * 4;
  float sx = 0.f, sy = 0.f, sz = 0.f, sw = 0.f;
#pragma unroll
  for (int r = 0; r < 9; ++r) {
    const float4 v = *reinterpret_cast<const float4*>(base + r * NDIM);
    sx += v.x; sy += v.y; sz += v.z; sw += v.w;
  }
  part[rg][col] = make_float4(sx, sy, sz, sw);
  __syncthreads();
  float mx = 0.f, my = 0.f, mz = 0.f, mw = 0.f;
  if (tid < 256) {
    const float4 a = part[0][tid], b4 = part[1][tid], c = part[2][tid], d4 = part[3][tid];
    const float inv = 1.0f / (float)NR;
    mx = (a.x + b4.x + c.x + d4.x) * inv;
    my = (a.y + b4.y + c.y + d4.y) * inv;
    mz = (a.z + b4.z + c.z + d4.z) * inv;
    mw = (a.w + b4.w + c.w + d4.w) * inv;
    *reinterpret_cast<float4*>(repr + (size_t)b * NDIM + tid * 4) = make_float4(mx, my, mz, mw);
    const float sq = wave_sum(mx * mx + my * my + mz * mz + mw * mw);
    if ((tid & 63) == 0) red[tid >> 6] = sq;
  }
  __syncthreads();
  if (tid == 0) sInv = 1.0f / (sqrtf(red[0] + red[1] + red[2] + red[3]) + 1e-8f);
  __syncthreads();
  if (tid < 256) {
    const float iv = sInv;
    *reinterpret_cast<float4*>(imgn + (size_t)b * NDIM + tid * 4) =
        make_float4(mx * iv, my * iv, mz * iv, mw * iv);
  }
}

// K5: layer1 split-K GEMM. grid (32 imggrp, 2 br, 8 kslab) x 512 thr.
// Block: 8 images x 128 h x 128-d slab. Thread: 2 h x 8 img register tile.
__global__ __launch_bounds__(512) void k_l1(const float* __restrict__ repr,
                                            const float* __restrict__ Wg1,
                                            const float* __restrict__ Wb1,
                                            float* __restrict__ hpart) {
  const int g = blockIdx.x, br = blockIdx.y, ks = blockIdx.z;
  const int b0 = g * 8;
  const int kbase = ks * 128;
  const int tid = threadIdx.x;
  const int h2 = tid & 63;
  const int ksub = tid >> 6;  // 0..7, 16 d each
  const float* __restrict__ W = br ? Wb1 : Wg1;
  __shared__ float shr[8][128];
  __shared__ float sacc[8][128][8];
  {
    const int im = tid >> 6, c2 = (tid & 63) * 2;
    *reinterpret_cast<float2*>(&shr[im][c2]) =
        *reinterpret_cast<const float2*>(repr + (size_t)(b0 + im) * NDIM + kbase + c2);
  }
  __syncthreads();
  float acc0[8] = {0, 0, 0, 0, 0, 0, 0, 0}, acc1[8] = {0, 0, 0, 0, 0, 0, 0, 0};
#pragma unroll
  for (int q = 0; q < 4; ++q) {
    const int dl = ksub * 16 + q * 4;
    const float* wq = W + (size_t)(kbase + dl) * HDIM + h2;
    const float wa0 = wq[0], wa1 = wq[128], wa2 = wq[256], wa3 = wq[384];
    const float wb0 = wq[64], wb1 = wq[192], wb2 = wq[320], wb3 = wq[448];
#pragma unroll
    for (int i = 0; i < 8; ++i) {
      const float4 s = *reinterpret_cast<const float4*>(&shr[i][dl]);
      acc0[i] += s.x * wa0 + s.y * wa1 + s.z * wa2 + s.w * wa3;
      acc1[i] += s.x * wb0 + s.y * wb1 + s.z * wb2 + s.w * wb3;
    }
  }
#pragma unroll
  for (int i = 0; i < 8; ++i) {
    sacc[ksub][h2][i] = acc0[i];
    sacc[ksub][h2 + 64][i] = acc1[i];
  }
  __syncthreads();
#pragma unroll
  for (int v = tid; v < 1024; v += 512) {
    const int hh = v & 127, im = v >> 7;
    float s = 0.f;
#pragma unroll
    for (int k2 = 0; k2 < 8; ++k2) s += sacc[k2][hh][im];
    hpart[(((size_t)ks * 2 + br) * NB + b0 + im) * HDIM + hh] = s;
  }
}

// K6: reduce hpart + bias + relu, layer2 both branches + derived u,a,bv,c,e.
// grid (64 imggrp of 4, 8 dgrp of 128) x 512 thr.
__global__ __launch_bounds__(512) void k_l2(
    const float* __restrict__ hpart, const float* __restrict__ bg1,
    const float* __restrict__ bb1, const float* __restrict__ Wg2,
    const float* __restrict__ bg2, const float* __restrict__ Wb2,
    const float* __restrict__ bb2, const float* __restrict__ imgn, float* __restrict__ uarr,
    float* __restrict__ aarr, float* __restrict__ bvarr, float* __restrict__ cpart,
    float* __restrict__ epart) {
  const int gb = blockIdx.x, dgrp = blockIdx.y;
  const int b0 = gb * 4;
  const int tid = threadIdx.x;
  const int dl = tid & 127;
  const int d = dgrp * 128 + dl;
  const int ig = tid >> 7;  // 0..3
  __shared__ float shh[2][4][HDIM];
  __shared__ float sred[8][2];
#pragma unroll
  for (int v = tid; v < 1024; v += 512) {
    const int brv = v >> 9, rem = v & 511, im = rem >> 7, hh = rem & 127;
    float s = 0.f;
#pragma unroll
    for (int k2 = 0; k2 < 8; ++k2)
      s += hpart[(((size_t)k2 * 2 + brv) * NB + b0 + im) * HDIM + hh];
    s += brv ? bb1[hh] : bg1[hh];
    shh[brv][im][hh] = fmaxf(s, 0.f);
  }
  __syncthreads();
  float ga = 0.f, ba = 0.f;
#pragma unroll 8
  for (int q = 0; q < 32; ++q) {
    const int h = q * 4;
    const float4 hg = *reinterpret_cast<const float4*>(&shh[0][ig][h]);
    const float4 hb = *reinterpret_cast<const float4*>(&shh[1][ig][h]);
    const float* wgp = Wg2 + (size_t)h * NDIM + d;
    const float* wbp = Wb2 + (size_t)h * NDIM + d;
    ga += hg.x * wgp[0] + hg.y * wgp[1024] + hg.z * wgp[2048] + hg.w * wgp[3072];
    ba += hb.x * wbp[0] + hb.y * wbp[1024] + hb.z * wbp[2048] + hb.w * wbp[3072];
  }
  const float ox = ga + bg2[d] + 1.0f;
  const float tb = ba + bb2[d];
  const size_t o = (size_t)(b0 + ig) * NDIM + d;
  const float nv = imgn[o];
  uarr[o] = nv * ox;
  aarr[o] = ox * ox;
  bvarr[o] = ox * tb;
  const float c = wave_sum(nv * tb);
  const float e = wave_sum(tb * tb);
  const int lane = tid & 63, wv = tid >> 6;
  if (lane == 0) { sred[wv][0] = c; sred[wv][1] = e; }
  __syncthreads();
  if (tid < 8) {
    const int im = tid >> 1, isE = tid & 1;
    const float vv = sred[im * 2][isE] + sred[im * 2 + 1][isE];
    (isE ? epart : cpart)[dgrp * NB + b0 + im] = vv;
  }
}

// K7: fused 3-dot tile kernel; 32x32 output tile, 2x2 per thread, split-K=4
#define DC 32
__global__ __launch_bounds__(256) void k_simtile(
    const float* __restrict__ uarr, const float* __restrict__ aarr,
    const float* __restrict__ bvarr, const float* __restrict__ pooled,
    const float* __restrict__ p2, float* __restrict__ pn, float* __restrict__ pa,
    float* __restrict__ pb) {
  __shared__ float su[32][36], sa[32][36], sb[32][36], sp[32][36], sq[32][36];
  const int tid = threadIdx.x;
  const int tx = tid & 15, ty = tid >> 4;
  const int i0 = blockIdx.x * 32, j0 = blockIdx.y * 32;
  const int k0 = blockIdx.z * 256;
  const int lr = tid >> 3;
  const int lc = (tid & 7) * 4;
  float an00 = 0, an01 = 0, an10 = 0, an11 = 0;
  float aa00 = 0, aa01 = 0, aa10 = 0, aa11 = 0;
  float ab00 = 0, ab01 = 0, ab10 = 0, ab11 = 0;
  for (int dc = k0; dc < k0 + 256; dc += DC) {
    __syncthreads();
    *reinterpret_cast<float4*>(&su[lr][lc]) =
        *reinterpret_cast<const float4*>(uarr + (i0 + lr) * NDIM + dc + lc);
    *reinterpret_cast<float4*>(&sa[lr][lc]) =
        *reinterpret_cast<const float4*>(aarr + (i0 + lr) * NDIM + dc + lc);
    *reinterpret_cast<float4*>(&sb[lr][lc]) =
        *reinterpret_cast<const float4*>(bvarr + (i0 + lr) * NDIM + dc + lc);
    *reinterpret_cast<float4*>(&sp[lr][lc]) =
        *reinterpret_cast<const float4*>(pooled + (j0 + lr) * NDIM + dc + lc);
    *reinterpret_cast<float4*>(&sq[lr][lc]) =
        *reinterpret_cast<const float4*>(p2 + (j0 + lr) * NDIM + dc + lc);
    __syncthreads();
#pragma unroll
    for (int dd = 0; dd < DC; dd += 4) {
      const float4 ru0 = *reinterpret_cast<const float4*>(&su[tx][dd]);
      const float4 ru1 = *reinterpret_cast<const float4*>(&su[tx + 16][dd]);
      const float4 ra0 = *reinterpret_cast<const float4*>(&sa[tx][dd]);
      const float4 ra1 = *reinterpret_cast<const float4*>(&sa[tx + 16][dd]);
      const float4 rb0 = *reinterpret_cast<const float4*>(&sb[tx][dd]);
      const float4 rb1 = *reinterpret_cast<const float4*>(&sb[tx + 16][dd]);
      const float4 rp0 = *reinterpret_cast<const float4*>(&sp[ty][dd]);
      const float4 rp1 = *reinterpret_cast<const float4*>(&sp[ty + 16][dd]);
      const float4 rq0 = *reinterpret_cast<const float4*>(&sq[ty][dd]);
      const float4 rq1 = *reinterpret_cast<const float4*>(&sq[ty + 16][dd]);
      an00 += dot4(ru0, rp0); an01 += dot4(ru0, rp1);
      an10 += dot4(ru1, rp0); an11 += dot4(ru1, rp1);
      aa00 += dot4(ra0, rq0); aa01 += dot4(ra0, rq1);
      aa10 += dot4(ra1, rq0); aa11 += dot4(ra1, rq1);
      ab00 += dot4(rb0, rp0); ab01 += dot4(rb0, rp1);
      ab10 += dot4(rb1, rp0); ab11 += dot4(rb1, rp1);
    }
  }
  const int s = blockIdx.z;
  const int i = i0 + tx, j = j0 + ty;
  size_t o = ((size_t)s * 256 + j) * 256 + i;
  pn[o] = an00; pa[o] = aa00; pb[o] = ab00;
  o = ((size_t)s * 256 + (j + 16)) * 256 + i;
  pn[o] = an01; pa[o] = aa01; pb[o] = ab01;
  o = ((size_t)s * 256 + j) * 256 + (i + 16);
  pn[o] = an10; pa[o] = aa10; pb[o] = ab10;
  o = ((size_t)s * 256 + (j + 16)) * 256 + (i + 16);
  pn[o] = an11; pa[o] = aa11; pb[o] = ab11;
}

// K8: split-K combine + epilogue (also sums the 8 c/e d-group partials)
__global__ __launch_bounds__(256) void k_reduce(const float* __restrict__ pn,
                                                const float* __restrict__ pa,
                                                const float* __restrict__ pb,
                                                const float* __restrict__ cpart,
                                                const float* __restrict__ epart,
                                                float* __restrict__ out) {
  const int j = blockIdx.x, i = threadIdx.x;
  const size_t base = (size_t)j * 256 + i;
  float n = 0.f, a = 0.f, b2 = 0.f;
#pragma unroll
  for (int s = 0; s < 4; ++s) {
    const size_t o = base + (size_t)s * 65536;
    n += pn[o]; a += pa[o]; b2 += pb[o];
  }
  float cv = 0.f, ev = 0.f;
#pragma unroll
  for (int s = 0; s < 8; ++s) { cv += cpart[s * NB + i]; ev += epart[s * NB + i]; }
  const float num = n + cv;
  const float den2 = a + 2.0f * b2 + ev;
  out[base] = num / (sqrtf(fmaxf(den2, 0.0f)) + 1e-8f);
}

extern "C" void kernel_launch(void* const* d_in, const int* in_sizes, int n_in,
                              void* d_out, int out_size, void* d_ws, size_t ws_size,
                              hipStream_t stream) {
  const float* img = (const float*)d_in[0];
  const float* cap = (const float*)d_in[1];
  const int* lens = (const int*)d_in[2];
  const float* Wg1 = (const float*)d_in[3];
  const float* bg1 = (const float*)d_in[4];
  const float* Wg2 = (const float*)d_in[5];
  const float* bg2 = (const float*)d_in[6];
  const float* Wb1 = (const float*)d_in[7];
  const float* bb1 = (const float*)d_in[8];
  const float* Wb2 = (const float*)d_in[9];
  const float* bb2 = (const float*)d_in[10];
  float* out = (float*)d_out;

  float* w = (float*)d_ws;
  float* fullsum = w; w += 2 * NB * NDIM;
  float* fullsq = w;  w += 2 * NB * NDIM;
  float* msum = w;    w += 2 * NB * NDIM;
  float* pooled = w;  w += NB * NDIM;
  float* p2 = w;      w += NB * NDIM;
  float* uarr = w;    w += NB * NDIM;
  float* aarr = w;    w += NB * NDIM;
  float* bvarr = w;   w += NB * NDIM;
  float* meanv = w;   w += NDIM;
  float* rstdv = w;   w += NDIM;
  float* cpart = w;   w += 8 * NB;
  float* epart = w;   w += 8 * NB;
  // Aliases (stream-ordered lifetimes):
  float* repr = fullsum;            // fullsum dead after k_stats
  float* imgn = fullsum + NB * NDIM;
  float* hpart = msum;              // msum dead after k_pool (8*2*256*128 floats)
  float* pn = fullsq;               // fullsq dead after k_stats
  float* pa = fullsq + NB * NDIM;
  float* pb = fullsum;              // repr dead after k_l1

  hipLaunchKernelGGL(k_cap1, dim3(512), dim3(256), 0, stream, cap, lens, fullsum, fullsq, msum);
  hipLaunchKernelGGL(k_stats, dim3(16), dim3(256), 0, stream, fullsum, fullsq, meanv, rstdv);
  hipLaunchKernelGGL(k_imgmean, dim3(NB), dim3(1024), 0, stream, img, repr, imgn);
  hipLaunchKernelGGL(k_pool, dim3(NB), dim3(256), 0, stream, msum, lens, meanv, rstdv, pooled, p2);
  hipLaunchKernelGGL(k_l1, dim3(32, 2, 8), dim3(512), 0, stream, repr, Wg1, Wb1, hpart);
  hipLaunchKernelGGL(k_l2, dim3(64, 8), dim3(512), 0, stream, hpart, bg1, bb1, Wg2, bg2, Wb2,
                     bb2, imgn, uarr, aarr, bvarr, cpart, epart);
  hipLaunchKernelGGL(k_simtile, dim3(8, 8, 4), dim3(256), 0, stream, uarr, aarr, bvarr, pooled,
                     p2, pn, pa, pb);
  hipLaunchKernelGGL(k_reduce, dim3(NB), dim3(256), 0, stream, pn, pa, pb, cpart, epart, out);
}